// Round 1
// baseline (41.096 us; speedup 1.0000x reference)
//
#include <hip/hip_runtime.h>
#include <math.h>
#include <stdint.h>

// PedestrianDetector v5: two-kernel, K-split-by-block, LDS-staged coalesced streaming.
//
// k1 (ped_part_kernel): 512 blocks x 512 threads (8 waves). Block pair (rb, half)
//   owns rows [rb*64, +64) x K-half [half*1024, +1024). Features are staged
//   global->LDS with __builtin_amdgcn_global_load_lds (16B, fully coalesced: each
//   inst = 64 lanes x 16B contiguous = 16 fully-consumed lines, vs v4's 64 partial
//   lines/inst). Double-buffered chunks of 64 d (16 KB tile), counted vmcnt(2) so
//   the HBM pipe never drains across barriers. LDS dest is linear; the global
//   SOURCE is inverse-XOR-swizzled per (row&7) and the ds_read_b128 applies the
//   same XOR -> conflict-free-minimum reads (rule 21 both-sides involution).
//   Compute keeps v4's scalar-W path: d is wave-uniform -> W through s_load/SGPR,
//   zero vector-memory cost. 8-wave LDS reduce -> partial[row][15] -> ws.
//   2 blocks/CU (64 KB LDS, 16 waves/CU): independent barrier domains overlap.
// k2 (ped_epi_kernel): per row, sum 2 K-half partials + bias, sigmoid, stable
//   top-3, threshold, pack (epilogue logic identical to harness-verified v4).

#define DCOLS 2048
#define RPB   64              // rows per block
#define NWAVE 8               // waves per block (512 threads)
#define KHALF 1024            // K range per block (K-split 2)
#define CCH   64              // chunk width (d) per staged tile
#define NCH   (KHALF / CCH)   // 16 chunks
#define TILEF (RPB * CCH)     // 4096 floats = 16 KB per buffer

__global__ __launch_bounds__(512, 4)
void ped_part_kernel(const float* __restrict__ feat,
                     const float* __restrict__ Wb,   // [2048][12]
                     const float* __restrict__ Wc,   // [2048][3]
                     float* __restrict__ ws)         // [nrows][2][16]
{
    __shared__ __align__(16) float lds[2][TILEF];    // 32 KB static; P-reduce aliases

    const int t    = threadIdx.x;
    const int lane = t & 63;
    const int w    = t >> 6;
    const int wu   = __builtin_amdgcn_readfirstlane(w);   // wave-uniform -> scalar W path

    const int half    = blockIdx.x & 1;
    const int rowBase = (blockIdx.x >> 1) * RPB;
    const int kbase   = half * KHALF;

    // Staging geometry (per chunk): wave wu issues 2x global_load_lds dwordx4.
    // Inst i covers rows [wu*8+i*4, +4): lane l -> row wu*8+i*4+(l>>4), row-slot u=l&15.
    // HW writes LDS linearly (base + lane*16); source slot = u ^ (row&7).
    const int rsub = lane >> 4;   // 0..3
    const int su   = lane & 15;   // 16B slot within the row's 64-float chunk

    float acc[15];
#pragma unroll
    for (int j = 0; j < 15; ++j) acc[j] = 0.0f;

    const float* fbase = feat + (size_t)rowBase * DCOLS + kbase;

    auto STAGE = [&](int c, int p) {
#pragma unroll
        for (int i = 0; i < 2; ++i) {
            const int r  = wu * 8 + i * 4 + rsub;
            const int gs = su ^ (r & 7);                       // inverse swizzle on source
            const float* g = fbase + (size_t)r * DCOLS + c * CCH + gs * 4;
            const float* l = &lds[p][(wu * 8 + i * 4) * CCH];  // wave-uniform base
            __builtin_amdgcn_global_load_lds(
                (const __attribute__((address_space(1))) void*)g,
                (__attribute__((address_space(3))) void*)l, 16, 0, 0);
        }
    };

    STAGE(0, 0);

    for (int c = 0; c < NCH; ++c) {
        if (c + 1 < NCH) {
            STAGE(c + 1, (c + 1) & 1);
            // FIFO vmcnt: 2 newest outstanding are stage(c+1) -> chunk c resident.
            asm volatile("s_waitcnt vmcnt(2)" ::: "memory");
        } else {
            asm volatile("s_waitcnt vmcnt(0)" ::: "memory");
        }
        asm volatile("s_barrier" ::: "memory");   // every wave's parts of chunk c resident

        const float* buf = &lds[c & 1][0];
#pragma unroll
        for (int q = 0; q < 2; ++q) {
            const int s = wu * 2 + q;             // 16B slot of this wave's d-slice
            // swizzled read: content = feat[row=lane][cbase + s*4 .. +3]
            const float4 f = *(const float4*)(buf + (size_t)lane * CCH
                                              + ((s ^ (lane & 7)) << 2));
            const int du = kbase + c * CCH + wu * 8 + q * 4;   // wave-uniform d
            const float* __restrict__ wbp = Wb + (size_t)du * 12;
            const float* __restrict__ wcp = Wc + (size_t)du * 3;
            const float fv[4] = { f.x, f.y, f.z, f.w };
#pragma unroll
            for (int j = 0; j < 4; ++j) {
                const float v = fv[j];
                acc[0]  += v * wbp[j * 12 + 0];
                acc[1]  += v * wbp[j * 12 + 1];
                acc[2]  += v * wbp[j * 12 + 2];
                acc[3]  += v * wbp[j * 12 + 3];
                acc[4]  += v * wbp[j * 12 + 4];
                acc[5]  += v * wbp[j * 12 + 5];
                acc[6]  += v * wbp[j * 12 + 6];
                acc[7]  += v * wbp[j * 12 + 7];
                acc[8]  += v * wbp[j * 12 + 8];
                acc[9]  += v * wbp[j * 12 + 9];
                acc[10] += v * wbp[j * 12 + 10];
                acc[11] += v * wbp[j * 12 + 11];
                acc[12] += v * wcp[j * 3 + 0];
                acc[13] += v * wcp[j * 3 + 1];
                acc[14] += v * wcp[j * 3 + 2];
            }
        }
        // ds_read data must be in registers before another wave's stage overwrites buf
        asm volatile("s_waitcnt lgkmcnt(0)" ::: "memory");
        asm volatile("s_barrier" ::: "memory");
    }

    // ---- reduce 8 wave-partials -> K-half partial, write to ws
    {
        float* P  = &lds[0][0];                         // 8*64*16 = 8192 floats (32 KB)
        float* pp = P + (size_t)(wu * RPB + lane) * 16;
#pragma unroll
        for (int j = 0; j < 15; ++j) pp[j] = acc[j];
    }
    __syncthreads();

    const float* P = &lds[0][0];
#pragma unroll
    for (int u0 = 0; u0 < 2; ++u0) {
        const int u = t + u0 * 512;                     // 512 threads cover 960 items
        if (u < RPB * 15) {
            const int r = u / 15;
            const int j = u - r * 15;
            float sum = 0.0f;
#pragma unroll
            for (int w2 = 0; w2 < NWAVE; ++w2)
                sum += P[(size_t)(w2 * RPB + r) * 16 + j];
            ws[((size_t)(rowBase + r) * 2 + half) * 16 + j] = sum;
        }
    }
}

__global__ __launch_bounds__(256, 4)
void ped_epi_kernel(const float* __restrict__ ws,
                    const float* __restrict__ bb,   // [12]
                    const float* __restrict__ bc,   // [3]
                    float* __restrict__ out, int nrows)
{
    const int r = blockIdx.x * 256 + threadIdx.x;
    if (r >= nrows) return;

    const float* p = ws + (size_t)r * 32;   // [half=0][16], [half=1][16], contiguous 128 B
    float s[15];
#pragma unroll
    for (int j = 0; j < 15; ++j)
        s[j] = p[j] + p[16 + j] + ((j < 12) ? bb[j] : bc[j - 12]);

    float conf[3];
#pragma unroll
    for (int a = 0; a < 3; ++a)
        conf[a] = 1.0f / (1.0f + __expf(-s[12 + a]));

    // stable top-3 (ties -> lower index), identical to v4
    int i0 = 0; float m0 = conf[0];
    if (conf[1] > m0) { i0 = 1; m0 = conf[1]; }
    if (conf[2] > m0) { i0 = 2; m0 = conf[2]; }
    const int ra = (i0 == 0) ? 1 : 0;
    const int rb = (i0 == 2) ? 1 : 2;
    int i1, i2;
    if (conf[rb] > conf[ra]) { i1 = rb; i2 = ra; }
    else                     { i1 = ra; i2 = rb; }
    const int idx[3] = { i0, i1, i2 };

    float* boxout  = out + (size_t)r * 12;
    float* confout = out + (size_t)nrows * 12 + (size_t)r * 3;
    float* valout  = out + (size_t)nrows * 15 + (size_t)r * 3;
#pragma unroll
    for (int sl = 0; sl < 3; ++sl) {
        const int   a   = idx[sl];
        const float cv  = conf[a];
        const bool  vld = cv > 0.5f;
        // static selects (no runtime-indexed private array -> no scratch, rule 20)
        const float b0 = (a == 0) ? s[0] : (a == 1) ? s[4]  : s[8];
        const float b1 = (a == 0) ? s[1] : (a == 1) ? s[5]  : s[9];
        const float b2 = (a == 0) ? s[2] : (a == 1) ? s[6]  : s[10];
        const float b3 = (a == 0) ? s[3] : (a == 1) ? s[7]  : s[11];
        float4 bx;
        bx.x = vld ? b0 : 0.0f;
        bx.y = vld ? b1 : 0.0f;
        bx.z = vld ? b2 : 0.0f;
        bx.w = vld ? b3 : 0.0f;
        *(float4*)(boxout + sl * 4) = bx;
        confout[sl] = cv;
        valout[sl]  = vld ? 1.0f : 0.0f;
    }
}

extern "C" void kernel_launch(void* const* d_in, const int* in_sizes, int n_in,
                              void* d_out, int out_size, void* d_ws, size_t ws_size,
                              hipStream_t stream) {
    const float* feat = (const float*)d_in[0];
    const float* Wb   = (const float*)d_in[1];
    const float* bb   = (const float*)d_in[2];
    const float* Wc   = (const float*)d_in[3];
    const float* bc   = (const float*)d_in[4];
    float* out = (float*)d_out;
    float* ws  = (float*)d_ws;    // needs nrows*2*16*4 B = 2 MB

    const int nrows = in_sizes[0] / DCOLS;          // 16384
    const int nb1   = (nrows / RPB) * 2;            // 512 blocks -> 2 blocks/CU

    ped_part_kernel<<<dim3(nb1), dim3(512), 0, stream>>>(feat, Wb, Wc, ws);
    ped_epi_kernel<<<dim3((nrows + 255) / 256), dim3(256), 0, stream>>>(
        ws, bb, bc, out, nrows);
}

// Round 2
// 40.059 us; speedup vs baseline: 1.0259x; 1.0259x over previous
//
#include <hip/hip_runtime.h>
#include <math.h>
#include <stdint.h>

// PedestrianDetector v6: single kernel, deep-pipelined LDS-staged streaming.
//
// 256 blocks x 1024 threads (16 waves), 1 block/CU. Block owns 64 rows x full K.
// K is processed in 32 chunks of 64 d (16 KB/chunk). 4 LDS buffers (64 KB), and a
// counted s_waitcnt vmcnt(3) keeps THREE chunks of staging in flight across the
// barriers at all times (T3/T4 pattern: never drain vmcnt in the loop). Per chunk
// each wave issues exactly ONE global_load_lds dwordx4 (1 KB, fully coalesced:
// 64 lanes x 16 B contiguous across 4 rows), so per-CU in-flight = 16 waves x 3 KB
// = 48 KB >> the ~9 KB latency-BW product -> request queue stays BW-paced, never
// drains to the latency floor (the suspected 2x loss in v4/v5).
//
// Swizzle (rule 21, both-sides involution): LDS dest linear; global SOURCE slot is
// u^(r&7); ds_read_b128 applies the same XOR -> optimal 8-cycle LDS reads.
// Compute keeps the scalar-W path: d wave-uniform -> W via s_load/SGPR, zero
// vector-memory cost. Reduce + epilogue copied verbatim from harness-verified v4
// (P stride 15, biased sums alias P behind a barrier, stable top-3, packed out).

#define DCOLS 2048
#define RPB   64              // rows per block
#define NW    16              // waves per block (1024 threads)
#define CCH   64              // chunk width in d (floats per row per chunk)
#define NCH   (DCOLS / CCH)   // 32 chunks
#define NBUF  4               // LDS chunk buffers (depth-3 prefetch)
#define TILEF (RPB * CCH)     // 4096 floats = 16 KB per buffer
#define PSTR  15              // partials row stride (odd -> conflict-free)

__global__ __launch_bounds__(1024, 4)
void ped_det_kernel(const float* __restrict__ feat,
                    const float* __restrict__ Wb,   // [2048][12]
                    const float* __restrict__ bb,   // [12]
                    const float* __restrict__ Wc,   // [2048][3]
                    const float* __restrict__ bc,   // [3]
                    float* __restrict__ out,
                    int nrows)
{
    __shared__ __align__(16) float lds[NBUF][TILEF];   // 65,536 B
    float* P = &lds[0][0];   // [16][64][15] partials (61,440 B) alias, after the loop
    float* S = P;            // [64][16] biased sums alias, behind a further barrier

    const int t    = threadIdx.x;
    const int lane = t & 63;
    const int w    = t >> 6;
    const int wu   = __builtin_amdgcn_readfirstlane(w);  // wave-uniform -> scalar paths

    const int rowBase = blockIdx.x * RPB;

    // --- staging geometry (fixed per lane): wave wu stages rows [wu*4, wu*4+4),
    // lane l -> row wu*4 + (l>>4), dest 16B-slot u = l&15 (HW: linear base+lane*16).
    // Source slot = u ^ (r&7) so that LDS slot p of row r holds global slot p^(r&7).
    const int rsub = lane >> 4;
    const int su   = lane & 15;
    const int rst  = wu * 4 + rsub;                       // staged row (block-rel)
    const size_t gofs = (size_t)rst * DCOLS + ((su ^ (rst & 7)) << 2);
    const float* fbase = feat + (size_t)rowBase * DCOLS;

    auto STAGE = [&](int c, int p) {
        const float* g = fbase + gofs + c * CCH;
        const float* l = &lds[p][wu * 4 * CCH];           // wave-uniform LDS base
        __builtin_amdgcn_global_load_lds(
            (const __attribute__((address_space(1))) void*)g,
            (__attribute__((address_space(3))) void*)l, 16, 0, 0);
    };

    // --- reader geometry (fixed): lane = row; wave wu consumes content slot wu
    // (d-range c*64 + wu*4 .. +4, wave-uniform). Swizzled read offset:
    const int roff = lane * CCH + ((wu ^ (lane & 7)) << 2);

    float acc[15];
#pragma unroll
    for (int j = 0; j < 15; ++j) acc[j] = 0.0f;

    // --- prologue: fill the pipe 3 deep (1 load per wave per chunk)
    STAGE(0, 0);
    STAGE(1, 1);
    STAGE(2, 2);

    for (int c = 0; c < NCH; ++c) {
        if (c + 3 < NCH) STAGE(c + 3, (c + 3) & (NBUF - 1));

        // counted FIFO wait: retire exactly chunk c's staging, keep 3 in flight
        const int rem = NCH - 1 - c;
        if (rem >= 3)      asm volatile("s_waitcnt vmcnt(3)" ::: "memory");
        else if (rem == 2) asm volatile("s_waitcnt vmcnt(2)" ::: "memory");
        else if (rem == 1) asm volatile("s_waitcnt vmcnt(1)" ::: "memory");
        else               asm volatile("s_waitcnt vmcnt(0)" ::: "memory");
        asm volatile("s_barrier" ::: "memory");   // all waves' pieces of chunk c resident

        const float* buf = &lds[c & (NBUF - 1)][0];
        const float4 f = *(const float4*)(buf + roff);   // content: feat[row=lane][du..du+3]

        const int du = c * CCH + wu * 4;                 // wave-uniform d
        const float* __restrict__ wbp = Wb + (size_t)du * 12;  // 48 contiguous floats
        const float* __restrict__ wcp = Wc + (size_t)du * 3;   // 12 contiguous floats
        const float fv[4] = { f.x, f.y, f.z, f.w };
#pragma unroll
        for (int j = 0; j < 4; ++j) {
            const float v = fv[j];
            acc[0]  += v * wbp[j * 12 + 0];
            acc[1]  += v * wbp[j * 12 + 1];
            acc[2]  += v * wbp[j * 12 + 2];
            acc[3]  += v * wbp[j * 12 + 3];
            acc[4]  += v * wbp[j * 12 + 4];
            acc[5]  += v * wbp[j * 12 + 5];
            acc[6]  += v * wbp[j * 12 + 6];
            acc[7]  += v * wbp[j * 12 + 7];
            acc[8]  += v * wbp[j * 12 + 8];
            acc[9]  += v * wbp[j * 12 + 9];
            acc[10] += v * wbp[j * 12 + 10];
            acc[11] += v * wbp[j * 12 + 11];
            acc[12] += v * wcp[j * 3 + 0];
            acc[13] += v * wcp[j * 3 + 1];
            acc[14] += v * wcp[j * 3 + 2];
        }

        // this wave's ds_read must land in registers before buffer c&3 is restaged
        asm volatile("s_waitcnt lgkmcnt(0)" ::: "memory");
        asm volatile("s_barrier" ::: "memory");
    }

    // ---- write per-wave partials (stride 15, odd -> <=2-way bank aliasing = free)
    {
        float* pp = &P[(wu * RPB + lane) * PSTR];
#pragma unroll
        for (int j = 0; j < 15; ++j) pp[j] = acc[j];
    }
    __syncthreads();

    // ---- reduce 16 wave-partials per (row, j), add bias -> register s
    float sval = 0.0f;
    int rl = 0, jj = 0;
    if (t < RPB * 15) {                 // u = t = rl*15 + j (consecutive -> conflict-free)
        rl = t / 15;
        jj = t % 15;
        float s = 0.0f;
#pragma unroll
        for (int w2 = 0; w2 < NW; ++w2)
            s += P[(w2 * RPB + rl) * PSTR + jj];
        s += (jj < 12) ? bb[jj] : bc[jj - 12];
        sval = s;
    }
    __syncthreads();                    // all P reads done before S (alias) is written

    if (t < RPB * 15)
        S[rl * 16 + jj] = sval;
    __syncthreads();

    // ---- epilogue: sigmoid, stable top-3 (ties -> lower index), threshold, store
    if (t < RPB) {
        const int r2 = t;
        float box[12];
#pragma unroll
        for (int j = 0; j < 12; ++j) box[j] = S[r2 * 16 + j];
        float conf[3];
#pragma unroll
        for (int a = 0; a < 3; ++a)
            conf[a] = 1.0f / (1.0f + __expf(-S[r2 * 16 + 12 + a]));

        int i0 = 0; float m0 = conf[0];
        if (conf[1] > m0) { i0 = 1; m0 = conf[1]; }
        if (conf[2] > m0) { i0 = 2; m0 = conf[2]; }
        const int ra = (i0 == 0) ? 1 : 0;
        const int rb = (i0 == 2) ? 1 : 2;
        int i1, i2;
        if (conf[rb] > conf[ra]) { i1 = rb; i2 = ra; }
        else                     { i1 = ra; i2 = rb; }
        const int idx[3] = { i0, i1, i2 };

        const int ro = blockIdx.x * RPB + r2;
        float* boxout  = out + (size_t)ro * 12;
        float* confout = out + (size_t)nrows * 12 + (size_t)ro * 3;
        float* valout  = out + (size_t)nrows * 15 + (size_t)ro * 3;
#pragma unroll
        for (int sl = 0; sl < 3; ++sl) {
            const int   a   = idx[sl];
            const float cv  = conf[a];
            const bool  vld = cv > 0.5f;
            float4 bx;
            bx.x = vld ? box[a * 4 + 0] : 0.0f;
            bx.y = vld ? box[a * 4 + 1] : 0.0f;
            bx.z = vld ? box[a * 4 + 2] : 0.0f;
            bx.w = vld ? box[a * 4 + 3] : 0.0f;
            *(float4*)(boxout + sl * 4) = bx;
            confout[sl] = cv;
            valout[sl]  = vld ? 1.0f : 0.0f;
        }
    }
}

extern "C" void kernel_launch(void* const* d_in, const int* in_sizes, int n_in,
                              void* d_out, int out_size, void* d_ws, size_t ws_size,
                              hipStream_t stream) {
    const float* feat = (const float*)d_in[0];
    const float* Wb   = (const float*)d_in[1];
    const float* bb   = (const float*)d_in[2];
    const float* Wc   = (const float*)d_in[3];
    const float* bc   = (const float*)d_in[4];
    float* out = (float*)d_out;

    const int nrows   = in_sizes[0] / DCOLS;   // 16384
    const int nblocks = nrows / RPB;           // 256 -> 1 block/CU

    ped_det_kernel<<<dim3(nblocks), dim3(1024), 0, stream>>>(
        feat, Wb, bb, Wc, bc, out, nrows);
}

// Round 3
// 39.995 us; speedup vs baseline: 1.0275x; 1.0016x over previous
//
#include <hip/hip_runtime.h>
#include <math.h>
#include <stdint.h>

// PedestrianDetector v7 = v6 + per-block K-phase rotation (anti-hotspot).
//
// Diagnosis driving this version: v4 (no barriers, per-lane loads), v5 (K-split,
// 2 blocks/CU) and v6 (deep-pipelined LDS staging) ALL land at 134MB/40us =
// 3.35 TB/s. The only shared property is the address pattern: a column-
// synchronized walk over rows of stride exactly 8 KB (2048 fp32). At each chunk
// step the whole GPU reads addresses congruent to c*256B mod 8KB -> any HBM
// channel / L3 slice interleave whose period divides 8KB collapses to a few
// active channels (classic 2-3x BW loss; also explains why 50% L3 residency
// gave zero gain - slice select is address-hashed too).
//
// Fix: block b walks chunks in order (c + b) mod 32, so at any instant the 256
// blocks collectively cover ALL 32 column offsets -> all channels/slices busy.
// Everything else is byte-identical to v6: 256 blocks x 1024 threads, 4x16KB
// LDS ring, depth-3 counted vmcnt, rule-21 XOR swizzle, scalar-W FMA loop,
// stride-15 partial reduce + stable top-3 epilogue (harness-verified).

#define DCOLS 2048
#define RPB   64              // rows per block
#define NW    16              // waves per block (1024 threads)
#define CCH   64              // chunk width in d (floats per row per chunk)
#define NCH   (DCOLS / CCH)   // 32 chunks
#define NBUF  4               // LDS chunk buffers (depth-3 prefetch)
#define TILEF (RPB * CCH)     // 4096 floats = 16 KB per buffer
#define PSTR  15              // partials row stride (odd -> conflict-free)

__global__ __launch_bounds__(1024, 4)
void ped_det_kernel(const float* __restrict__ feat,
                    const float* __restrict__ Wb,   // [2048][12]
                    const float* __restrict__ bb,   // [12]
                    const float* __restrict__ Wc,   // [2048][3]
                    const float* __restrict__ bc,   // [3]
                    float* __restrict__ out,
                    int nrows)
{
    __shared__ __align__(16) float lds[NBUF][TILEF];   // 65,536 B
    float* P = &lds[0][0];   // [16][64][15] partials (61,440 B) alias, after the loop
    float* S = P;            // [64][16] biased sums alias, behind a further barrier

    const int t    = threadIdx.x;
    const int lane = t & 63;
    const int w    = t >> 6;
    const int wu   = __builtin_amdgcn_readfirstlane(w);  // wave-uniform -> scalar paths

    const int rowBase = blockIdx.x * RPB;
    // per-block chunk-phase rotation: block b starts its column walk at chunk b%32
    const int bph = (int)(blockIdx.x) & (NCH - 1);

    // --- staging geometry (fixed per lane): wave wu stages rows [wu*4, wu*4+4),
    // lane l -> row wu*4 + (l>>4), dest 16B-slot u = l&15 (HW: linear base+lane*16).
    // Source slot = u ^ (r&7) so that LDS slot p of row r holds global slot p^(r&7).
    const int rsub = lane >> 4;
    const int su   = lane & 15;
    const int rst  = wu * 4 + rsub;                       // staged row (block-rel)
    const size_t gofs = (size_t)rst * DCOLS + ((su ^ (rst & 7)) << 2);
    const float* fbase = feat + (size_t)rowBase * DCOLS;

    auto STAGE = [&](int c, int p) {
        const int ca = (c + bph) & (NCH - 1);             // rotated chunk id
        const float* g = fbase + gofs + ca * CCH;
        const float* l = &lds[p][wu * 4 * CCH];           // wave-uniform LDS base
        __builtin_amdgcn_global_load_lds(
            (const __attribute__((address_space(1))) void*)g,
            (__attribute__((address_space(3))) void*)l, 16, 0, 0);
    };

    // --- reader geometry (fixed): lane = row; wave wu consumes content slot wu
    // (d-range ca*64 + wu*4 .. +4, wave-uniform). Swizzled read offset:
    const int roff = lane * CCH + ((wu ^ (lane & 7)) << 2);

    float acc[15];
#pragma unroll
    for (int j = 0; j < 15; ++j) acc[j] = 0.0f;

    // --- prologue: fill the pipe 3 deep (1 load per wave per chunk)
    STAGE(0, 0);
    STAGE(1, 1);
    STAGE(2, 2);

    for (int c = 0; c < NCH; ++c) {
        if (c + 3 < NCH) STAGE(c + 3, (c + 3) & (NBUF - 1));

        // counted FIFO wait: retire exactly chunk c's staging, keep 3 in flight
        const int rem = NCH - 1 - c;
        if (rem >= 3)      asm volatile("s_waitcnt vmcnt(3)" ::: "memory");
        else if (rem == 2) asm volatile("s_waitcnt vmcnt(2)" ::: "memory");
        else if (rem == 1) asm volatile("s_waitcnt vmcnt(1)" ::: "memory");
        else               asm volatile("s_waitcnt vmcnt(0)" ::: "memory");
        asm volatile("s_barrier" ::: "memory");   // all waves' pieces of chunk c resident

        const float* buf = &lds[c & (NBUF - 1)][0];
        const float4 f = *(const float4*)(buf + roff);   // feat[row=lane][du..du+3]

        const int ca = (c + bph) & (NCH - 1);
        const int du = ca * CCH + wu * 4;                // wave-uniform d
        const float* __restrict__ wbp = Wb + (size_t)du * 12;  // 48 contiguous floats
        const float* __restrict__ wcp = Wc + (size_t)du * 3;   // 12 contiguous floats
        const float fv[4] = { f.x, f.y, f.z, f.w };
#pragma unroll
        for (int j = 0; j < 4; ++j) {
            const float v = fv[j];
            acc[0]  += v * wbp[j * 12 + 0];
            acc[1]  += v * wbp[j * 12 + 1];
            acc[2]  += v * wbp[j * 12 + 2];
            acc[3]  += v * wbp[j * 12 + 3];
            acc[4]  += v * wbp[j * 12 + 4];
            acc[5]  += v * wbp[j * 12 + 5];
            acc[6]  += v * wbp[j * 12 + 6];
            acc[7]  += v * wbp[j * 12 + 7];
            acc[8]  += v * wbp[j * 12 + 8];
            acc[9]  += v * wbp[j * 12 + 9];
            acc[10] += v * wbp[j * 12 + 10];
            acc[11] += v * wbp[j * 12 + 11];
            acc[12] += v * wcp[j * 3 + 0];
            acc[13] += v * wcp[j * 3 + 1];
            acc[14] += v * wcp[j * 3 + 2];
        }

        // this wave's ds_read must land in registers before buffer c&3 is restaged
        asm volatile("s_waitcnt lgkmcnt(0)" ::: "memory");
        asm volatile("s_barrier" ::: "memory");
    }

    // ---- write per-wave partials (stride 15, odd -> <=2-way bank aliasing = free)
    {
        float* pp = &P[(wu * RPB + lane) * PSTR];
#pragma unroll
        for (int j = 0; j < 15; ++j) pp[j] = acc[j];
    }
    __syncthreads();

    // ---- reduce 16 wave-partials per (row, j), add bias -> register s
    float sval = 0.0f;
    int rl = 0, jj = 0;
    if (t < RPB * 15) {                 // u = t = rl*15 + j (consecutive -> conflict-free)
        rl = t / 15;
        jj = t % 15;
        float s = 0.0f;
#pragma unroll
        for (int w2 = 0; w2 < NW; ++w2)
            s += P[(w2 * RPB + rl) * PSTR + jj];
        s += (jj < 12) ? bb[jj] : bc[jj - 12];
        sval = s;
    }
    __syncthreads();                    // all P reads done before S (alias) is written

    if (t < RPB * 15)
        S[rl * 16 + jj] = sval;
    __syncthreads();

    // ---- epilogue: sigmoid, stable top-3 (ties -> lower index), threshold, store
    if (t < RPB) {
        const int r2 = t;
        float box[12];
#pragma unroll
        for (int j = 0; j < 12; ++j) box[j] = S[r2 * 16 + j];
        float conf[3];
#pragma unroll
        for (int a = 0; a < 3; ++a)
            conf[a] = 1.0f / (1.0f + __expf(-S[r2 * 16 + 12 + a]));

        int i0 = 0; float m0 = conf[0];
        if (conf[1] > m0) { i0 = 1; m0 = conf[1]; }
        if (conf[2] > m0) { i0 = 2; m0 = conf[2]; }
        const int ra = (i0 == 0) ? 1 : 0;
        const int rb = (i0 == 2) ? 1 : 2;
        int i1, i2;
        if (conf[rb] > conf[ra]) { i1 = rb; i2 = ra; }
        else                     { i1 = ra; i2 = rb; }
        const int idx[3] = { i0, i1, i2 };

        const int ro = blockIdx.x * RPB + r2;
        float* boxout  = out + (size_t)ro * 12;
        float* confout = out + (size_t)nrows * 12 + (size_t)ro * 3;
        float* valout  = out + (size_t)nrows * 15 + (size_t)ro * 3;
#pragma unroll
        for (int sl = 0; sl < 3; ++sl) {
            const int   a   = idx[sl];
            const float cv  = conf[a];
            const bool  vld = cv > 0.5f;
            float4 bx;
            bx.x = vld ? box[a * 4 + 0] : 0.0f;
            bx.y = vld ? box[a * 4 + 1] : 0.0f;
            bx.z = vld ? box[a * 4 + 2] : 0.0f;
            bx.w = vld ? box[a * 4 + 3] : 0.0f;
            *(float4*)(boxout + sl * 4) = bx;
            confout[sl] = cv;
            valout[sl]  = vld ? 1.0f : 0.0f;
        }
    }
}

extern "C" void kernel_launch(void* const* d_in, const int* in_sizes, int n_in,
                              void* d_out, int out_size, void* d_ws, size_t ws_size,
                              hipStream_t stream) {
    const float* feat = (const float*)d_in[0];
    const float* Wb   = (const float*)d_in[1];
    const float* bb   = (const float*)d_in[2];
    const float* Wc   = (const float*)d_in[3];
    const float* bc   = (const float*)d_in[4];
    float* out = (float*)d_out;

    const int nrows   = in_sizes[0] / DCOLS;   // 16384
    const int nblocks = nrows / RPB;           // 256 -> 1 block/CU

    ped_det_kernel<<<dim3(nblocks), dim3(1024), 0, stream>>>(
        feat, Wb, bb, Wc, bc, out, nrows);
}